// Round 5
// baseline (1173.099 us; speedup 1.0000x reference)
//
#include <hip/hip_runtime.h>
#include <hip/hip_bf16.h>
#include <stdint.h>

#define C_DIM 768
#define HW 16384
#define EPSF 1e-8f

typedef __attribute__((ext_vector_type(4))) int i32x4;

// ---------------- Kernel A: per-channel means over spatial dim ----------------
__global__ __launch_bounds__(256) void k_means(const float* __restrict__ x,
                                               const float* __restrict__ s,
                                               float* __restrict__ meanA,
                                               float* __restrict__ meanB) {
  int ch = blockIdx.x;
  const float* src = (ch < C_DIM) ? (x + (size_t)ch * HW) : (s + (size_t)(ch - C_DIM) * HW);
  int t = threadIdx.x;
  float acc = 0.f;
  for (int i = t; i < HW; i += 256) acc += src[i];
  __shared__ float red[256];
  red[t] = acc;
  __syncthreads();
  for (int o = 128; o > 0; o >>= 1) {
    if (t < o) red[t] += red[t + o];
    __syncthreads();
  }
  if (t == 0) {
    float m = red[0] * (1.0f / HW);
    if (ch < C_DIM) meanA[ch] = m; else meanB[ch - C_DIM] = m;
  }
}

// ---------------- Kernel S: per-position stats ----------------
// Per position p: quant scales (maxabs of centered a/b), raw norms, centered-b
// norm (invbn), and the cross terms u[p]=ac·mb, v[p]=ma·bc for dot reconstruction.
__global__ __launch_bounds__(256) void k_stats(const float* __restrict__ x,
                                               const float* __restrict__ s,
                                               const float* __restrict__ meanA,
                                               const float* __restrict__ meanB,
                                               float* __restrict__ qsa,
                                               float* __restrict__ qsb,
                                               float* __restrict__ eff,
                                               float* __restrict__ invbn,
                                               float* __restrict__ rawNA,
                                               float* __restrict__ rawNB,
                                               float* __restrict__ u,
                                               float* __restrict__ v) {
  __shared__ float lma[C_DIM], lmb[C_DIM];
  __shared__ float red[7 * 256];
  int t = threadIdx.x;
  int p0 = blockIdx.x * 64;
  for (int c = t; c < C_DIM; c += 256) { lma[c] = meanA[c]; lmb[c] = meanB[c]; }
  __syncthreads();
  int pl = t & 63, cl = t >> 6;
  int p = p0 + pl;
  float maxa = 0.f, ssaR = 0.f, maxb = 0.f, ssbC = 0.f, ssbR = 0.f, uacc = 0.f, vacc = 0.f;
  for (int c = cl; c < C_DIM; c += 4) {
    float av = x[(size_t)c * HW + p];
    float bv = s[(size_t)c * HW + p];
    float ac = av - lma[c];
    float bc = bv - lmb[c];
    maxa = fmaxf(maxa, fabsf(ac));
    maxb = fmaxf(maxb, fabsf(bc));
    ssaR += av * av;
    ssbC += bc * bc;
    ssbR += bv * bv;
    uacc += ac * lmb[c];
    vacc += bc * lma[c];
  }
  red[t] = maxa; red[256 + t] = ssaR; red[512 + t] = maxb;
  red[768 + t] = ssbC; red[1024 + t] = ssbR; red[1280 + t] = uacc; red[1536 + t] = vacc;
  __syncthreads();
  if (t < 64) {
    float ma = fmaxf(fmaxf(red[t], red[t + 64]), fmaxf(red[t + 128], red[t + 192]));
    float sa = red[256 + t] + red[256 + t + 64] + red[256 + t + 128] + red[256 + t + 192];
    float mb = fmaxf(fmaxf(red[512 + t], red[512 + t + 64]), fmaxf(red[512 + t + 128], red[512 + t + 192]));
    float sc = red[768 + t] + red[768 + t + 64] + red[768 + t + 128] + red[768 + t + 192];
    float sb = red[1024 + t] + red[1024 + t + 64] + red[1024 + t + 128] + red[1024 + t + 192];
    float uu = red[1280 + t] + red[1280 + t + 64] + red[1280 + t + 128] + red[1280 + t + 192];
    float vv = red[1536 + t] + red[1536 + t + 64] + red[1536 + t + 128] + red[1536 + t + 192];
    ma = fmaxf(ma, 1e-20f);
    mb = fmaxf(mb, 1e-20f);
    float ib = 1.0f / (sqrtf(sc + EPSF) + EPSF);
    qsa[p0 + t] = 127.0f / ma;
    qsb[p0 + t] = 127.0f / mb;
    eff[p0 + t] = (mb * (1.0f / 127.0f)) * ib;
    invbn[p0 + t] = ib;
    rawNA[p0 + t] = sqrtf(sa);
    rawNB[p0 + t] = sqrtf(sb);
    u[p0 + t] = uu;
    v[p0 + t] = vv;
  }
}

// ---------------- Kernel Q: transpose + int8 quantize + MFMA-native pack -------
__global__ __launch_bounds__(256) void k_quant(const float* __restrict__ x,
                                               const float* __restrict__ s,
                                               const float* __restrict__ meanA,
                                               const float* __restrict__ meanB,
                                               const float* __restrict__ qsa,
                                               const float* __restrict__ qsb,
                                               signed char* __restrict__ qa,
                                               signed char* __restrict__ Bp) {
  __shared__ float la[64 * 33];
  __shared__ float lb[64 * 33];
  __shared__ float lma[C_DIM], lmb[C_DIM];
  int t = threadIdx.x;
  int j0 = blockIdx.x * 64;
  for (int c = t; c < C_DIM; c += 256) { lma[c] = meanA[c]; lmb[c] = meanB[c]; }

  int wj = t >> 2;
  int wk = (t & 3) * 8;
  int p = j0 + wj;
  float sa = qsa[p];
  float sb = qsb[p];
  int g = p >> 4;
  int laneB = p & 15;

  for (int c0 = 0; c0 < C_DIM; c0 += 32) {
    __syncthreads();
#pragma unroll
    for (int sIt = 0; sIt < 8; ++sIt) {
      int idx = t + sIt * 256;
      int r = idx >> 6, cc = idx & 63;
      la[cc * 33 + r] = x[(size_t)(c0 + r) * HW + j0 + cc];
      lb[cc * 33 + r] = s[(size_t)(c0 + r) * HW + j0 + cc];
    }
    __syncthreads();
    unsigned long long pkA = 0, pkB = 0;
#pragma unroll
    for (int uu = 0; uu < 8; ++uu) {
      int c = c0 + wk + uu;
      float av = (la[wj * 33 + wk + uu] - lma[c]) * sa;
      float bv = (lb[wj * 33 + wk + uu] - lmb[c]) * sb;
      int qA = (int)rintf(fminf(fmaxf(av, -127.f), 127.f));
      int qB = (int)rintf(fminf(fmaxf(bv, -127.f), 127.f));
      pkA |= ((unsigned long long)(unsigned char)(signed char)qA) << (8 * uu);
      pkB |= ((unsigned long long)(unsigned char)(signed char)qB) << (8 * uu);
    }
    *(unsigned long long*)(qa + (size_t)p * C_DIM + c0 + wk) = pkA;
    int k0 = c0 + wk;
    int sblk = k0 >> 6;
    int quad = (k0 & 63) >> 4;
    int e0 = k0 & 15;
    *(unsigned long long*)(Bp + (size_t)(g * 12 + sblk) * 1024 + (laneB | (quad << 4)) * 16 + e0) = pkB;
  }
}

// ---------------- Kernel G: LDS-free i8 MFMA GEMM + fused argmax ----------------
// XCD swizzle: xcd=b&7 (HW round-robin), quarter=xcd>>1 -> each XCD streams ONE
// 3 MB Bp quarter (L2-resident). Body order: MFMA(cur) -> prefetch(g+2) ->
// epilogue; no barriers. Even a conservative vmcnt(0) before the MFMAs only
// waits on loads issued a full body (~2000 cyc) earlier.
__global__ __launch_bounds__(256, 1) void k_gemm_argmax(
    const signed char* __restrict__ qa,
    const signed char* __restrict__ Bp,
    const float* __restrict__ eff,
    unsigned long long* __restrict__ best) {
  int t = threadIdx.x;
  int lane = t & 63, w = t >> 6;
  int m = lane & 15, q = lane >> 4;
  int b = blockIdx.x;
  int xcd = b & 7, slotb = b >> 3;
  int bq = xcd >> 1;                    // quarter 0..3 (2 XCDs per quarter)
  int rg = slotb | ((xcd & 1) << 5);    // row-group 0..63
  int i0 = rg * 256;
  int g0 = bq * 256, g1 = g0 + 256;

  const i32x4* qaV = (const i32x4*)qa;
  const i32x4* BpV = (const i32x4*)Bp;

  i32x4 a_res[4][12];
#pragma unroll
  for (int tm = 0; tm < 4; ++tm) {
    int row = i0 + w * 64 + tm * 16 + m;
#pragma unroll
    for (int s = 0; s < 12; ++s)
      a_res[tm][s] = qaV[(size_t)row * 48 + s * 4 + q];
  }

  float bestv[4][4];
  int bestj[4][4];
#pragma unroll
  for (int tm = 0; tm < 4; ++tm)
#pragma unroll
    for (int r = 0; r < 4; ++r) { bestv[tm][r] = -3.0e38f; bestj[tm][r] = 0x7FFFFFFF; }

  i32x4 f0[12], f1[12];
  float e0, e1;
#pragma unroll
  for (int s = 0; s < 12; ++s) f0[s] = BpV[(size_t)(g0 * 12 + s) * 64 + lane];
  e0 = eff[(g0 << 4) + m];
#pragma unroll
  for (int s = 0; s < 12; ++s) f1[s] = BpV[(size_t)((g0 + 1) * 12 + s) * 64 + lane];
  e1 = eff[((g0 + 1) << 4) + m];

#define GBODY(FC, EC, GG)                                                         \
  {                                                                               \
    i32x4 acc0 = {0,0,0,0}, acc1 = {0,0,0,0}, acc2 = {0,0,0,0}, acc3 = {0,0,0,0}; \
    _Pragma("unroll")                                                             \
    for (int s = 0; s < 12; ++s) {                                                \
      acc0 = __builtin_amdgcn_mfma_i32_16x16x64_i8(a_res[0][s], FC[s], acc0, 0, 0, 0); \
      acc1 = __builtin_amdgcn_mfma_i32_16x16x64_i8(a_res[1][s], FC[s], acc1, 0, 0, 0); \
      acc2 = __builtin_amdgcn_mfma_i32_16x16x64_i8(a_res[2][s], FC[s], acc2, 0, 0, 0); \
      acc3 = __builtin_amdgcn_mfma_i32_16x16x64_i8(a_res[3][s], FC[s], acc3, 0, 0, 0); \
    }                                                                             \
    int _gn = (GG) + 2;                                                           \
    if (_gn >= g1) _gn = g1 - 1;                                                  \
    _Pragma("unroll")                                                             \
    for (int s = 0; s < 12; ++s) FC[s] = BpV[(size_t)(_gn * 12 + s) * 64 + lane]; \
    float _ev = EC;                                                               \
    EC = eff[(_gn << 4) + m];                                                     \
    int jj = ((GG) << 4) + m;                                                     \
    _Pragma("unroll")                                                             \
    for (int r = 0; r < 4; ++r) {                                                 \
      float v0 = (float)acc0[r] * _ev;                                            \
      float v1 = (float)acc1[r] * _ev;                                            \
      float v2 = (float)acc2[r] * _ev;                                            \
      float v3 = (float)acc3[r] * _ev;                                            \
      if (v0 > bestv[0][r]) { bestv[0][r] = v0; bestj[0][r] = jj; }               \
      if (v1 > bestv[1][r]) { bestv[1][r] = v1; bestj[1][r] = jj; }               \
      if (v2 > bestv[2][r]) { bestv[2][r] = v2; bestj[2][r] = jj; }               \
      if (v3 > bestv[3][r]) { bestv[3][r] = v3; bestj[3][r] = jj; }               \
    }                                                                             \
  }

  for (int g = g0; g < g1; g += 2) {
    GBODY(f0, e0, g)
    GBODY(f1, e1, g + 1)
  }
#undef GBODY

#pragma unroll
  for (int tm = 0; tm < 4; ++tm) {
#pragma unroll
    for (int r = 0; r < 4; ++r) {
      float bv = bestv[tm][r];
      int bj = bestj[tm][r];
#pragma unroll
      for (int off = 1; off < 16; off <<= 1) {
        float ov = __shfl_xor(bv, off, 64);
        int oj = __shfl_xor(bj, off, 64);
        if (ov > bv || (ov == bv && oj < bj)) { bv = ov; bj = oj; }
      }
      if (m == 0) {
        int i = i0 + w * 64 + tm * 16 + q * 4 + r;
        unsigned key = __float_as_uint(bv);
        key = (key & 0x80000000u) ? ~key : (key | 0x80000000u);
        unsigned long long packed =
            ((unsigned long long)key << 32) | (unsigned long long)(0xFFFFFFFFu - (unsigned)bj);
        atomicMax(&best[i], packed);
      }
    }
  }
}

// ---------------- Kernel D: final loss via analytic dot reconstruction ----------
// dot(a_i,b_j) = dotcc + u[i] + v[j] + w;  dotcc = bv/(invbn[j]*qsa[i]) where bv
// is the winning scaled score recovered from the packed atomic key.
__global__ __launch_bounds__(256) void k_loss2(const float* __restrict__ meanA,
                                               const float* __restrict__ meanB,
                                               const unsigned long long* __restrict__ best,
                                               const float* __restrict__ rawNA,
                                               const float* __restrict__ rawNB,
                                               const float* __restrict__ invbn,
                                               const float* __restrict__ qsa,
                                               const float* __restrict__ u,
                                               const float* __restrict__ v,
                                               float* __restrict__ out) {
  __shared__ float red[256];
  int t = threadIdx.x;
  float wp = 0.f;
  for (int c = t; c < C_DIM; c += 256) wp += meanA[c] * meanB[c];
  red[t] = wp;
  __syncthreads();
  for (int o = 128; o > 0; o >>= 1) {
    if (t < o) red[t] += red[t + o];
    __syncthreads();
  }
  float wdot = red[0];
  __syncthreads();

  int i = blockIdx.x * 256 + t;
  unsigned long long pk = best[i];
  unsigned key = (unsigned)(pk >> 32);
  unsigned fb = (key & 0x80000000u) ? (key & 0x7FFFFFFFu) : ~key;
  float bv = __uint_as_float(fb);
  int j = (int)(0xFFFFFFFFu - (unsigned)(pk & 0xFFFFFFFFull));
  float dotcc = bv / (invbn[j] * qsa[i]);
  float dot = dotcc + u[i] + v[j] + wdot;
  float cs = dot / ((rawNA[i] + EPSF) * (rawNB[j] + EPSF));
  red[t] = (1.0f - cs) * (1.0f / HW);
  __syncthreads();
  for (int o = 128; o > 0; o >>= 1) {
    if (t < o) red[t] += red[t + o];
    __syncthreads();
  }
  if (t == 0) atomicAdd(out, red[0]);
}

// ---------------- Launch ----------------
extern "C" void kernel_launch(void* const* d_in, const int* in_sizes, int n_in,
                              void* d_out, int out_size, void* d_ws, size_t ws_size,
                              hipStream_t stream) {
  const float* x = (const float*)d_in[0];
  const float* s = (const float*)d_in[1];
  char* ws = (char*)d_ws;
  float* meanA = (float*)(ws + 0);
  float* meanB = (float*)(ws + 4096);
  float* rawNA = (float*)(ws + 8192);
  float* rawNB = (float*)(ws + 73728);
  float* eff   = (float*)(ws + 139264);
  float* qsa   = (float*)(ws + 204800);
  float* qsb   = (float*)(ws + 270336);
  float* invbn = (float*)(ws + 335872);
  float* u     = (float*)(ws + 401408);
  float* v     = (float*)(ws + 466944);
  unsigned long long* best = (unsigned long long*)(ws + 532480);
  signed char* qa = (signed char*)(ws + 663552);
  signed char* Bp = (signed char*)(ws + 663552 + 12582912);
  float* out = (float*)d_out;

  hipMemsetAsync(best, 0, HW * sizeof(unsigned long long), stream);
  hipMemsetAsync(out, 0, sizeof(float), stream);
  k_means<<<2 * C_DIM, 256, 0, stream>>>(x, s, meanA, meanB);
  k_stats<<<HW / 64, 256, 0, stream>>>(x, s, meanA, meanB, qsa, qsb, eff, invbn, rawNA, rawNB, u, v);
  k_quant<<<HW / 64, 256, 0, stream>>>(x, s, meanA, meanB, qsa, qsb, qa, Bp);
  k_gemm_argmax<<<256, 256, 0, stream>>>(qa, Bp, eff, best);
  k_loss2<<<HW / 256, 256, 0, stream>>>(meanA, meanB, best, rawNA, rawNB, invbn, qsa, u, v, out);
}

// Round 6
// 400.948 us; speedup vs baseline: 2.9258x; 2.9258x over previous
//
#include <hip/hip_runtime.h>
#include <hip/hip_bf16.h>
#include <stdint.h>

#define C_DIM 768
#define HW 16384
#define EPSF 1e-8f
#define GPQ 256            // groups (16 cols) per quarter

typedef __attribute__((ext_vector_type(4))) int i32x4;

// ---------------- Kernel A: per-channel means over spatial dim ----------------
__global__ __launch_bounds__(256) void k_means(const float* __restrict__ x,
                                               const float* __restrict__ s,
                                               float* __restrict__ meanA,
                                               float* __restrict__ meanB) {
  int ch = blockIdx.x;
  const float* src = (ch < C_DIM) ? (x + (size_t)ch * HW) : (s + (size_t)(ch - C_DIM) * HW);
  int t = threadIdx.x;
  float acc = 0.f;
  for (int i = t; i < HW; i += 256) acc += src[i];
  __shared__ float red[256];
  red[t] = acc;
  __syncthreads();
  for (int o = 128; o > 0; o >>= 1) {
    if (t < o) red[t] += red[t + o];
    __syncthreads();
  }
  if (t == 0) {
    float m = red[0] * (1.0f / HW);
    if (ch < C_DIM) meanA[ch] = m; else meanB[ch - C_DIM] = m;
  }
}

// ---------------- Kernel P: fused stats + quantize + pack ----------------
// Phase 1 (stats): per position p: maxabs of centered a/b, raw norms, centered-b
// norm, cross terms u,v. Phase 2 (quant): transpose-tile, int8 quantize, pack
// qa[p][c] row-major and Bp in MFMA-native 1024B blocks.
__global__ __launch_bounds__(256) void k_prepq(const float* __restrict__ x,
                                               const float* __restrict__ s,
                                               const float* __restrict__ meanA,
                                               const float* __restrict__ meanB,
                                               float* __restrict__ qsaG,
                                               float* __restrict__ effG,
                                               float* __restrict__ invbnG,
                                               float* __restrict__ rawNA,
                                               float* __restrict__ rawNB,
                                               float* __restrict__ uG,
                                               float* __restrict__ vG,
                                               signed char* __restrict__ qa,
                                               signed char* __restrict__ Bp) {
  __shared__ float lma[C_DIM], lmb[C_DIM];
  __shared__ float red[7 * 256];
  __shared__ float la[64 * 33], lb[64 * 33];
  __shared__ float lsa[64], lsb[64];
  int t = threadIdx.x;
  int j0 = blockIdx.x * 64;
  for (int c = t; c < C_DIM; c += 256) { lma[c] = meanA[c]; lmb[c] = meanB[c]; }
  __syncthreads();

  // ---- phase 1: stats ----
  {
    int pl = t & 63, cl = t >> 6;
    int p = j0 + pl;
    float maxa = 0.f, ssaR = 0.f, maxb = 0.f, ssbC = 0.f, ssbR = 0.f, uacc = 0.f, vacc = 0.f;
    for (int c = cl; c < C_DIM; c += 4) {
      float av = x[(size_t)c * HW + p];
      float bv = s[(size_t)c * HW + p];
      float ac = av - lma[c];
      float bc = bv - lmb[c];
      maxa = fmaxf(maxa, fabsf(ac));
      maxb = fmaxf(maxb, fabsf(bc));
      ssaR += av * av;
      ssbC += bc * bc;
      ssbR += bv * bv;
      uacc += ac * lmb[c];
      vacc += bc * lma[c];
    }
    red[t] = maxa; red[256 + t] = ssaR; red[512 + t] = maxb;
    red[768 + t] = ssbC; red[1024 + t] = ssbR; red[1280 + t] = uacc; red[1536 + t] = vacc;
    __syncthreads();
    if (t < 64) {
      float ma = fmaxf(fmaxf(red[t], red[t + 64]), fmaxf(red[t + 128], red[t + 192]));
      float sa = red[256 + t] + red[256 + t + 64] + red[256 + t + 128] + red[256 + t + 192];
      float mb = fmaxf(fmaxf(red[512 + t], red[512 + t + 64]), fmaxf(red[512 + t + 128], red[512 + t + 192]));
      float sc = red[768 + t] + red[768 + t + 64] + red[768 + t + 128] + red[768 + t + 192];
      float sb = red[1024 + t] + red[1024 + t + 64] + red[1024 + t + 128] + red[1024 + t + 192];
      float uu = red[1280 + t] + red[1280 + t + 64] + red[1280 + t + 128] + red[1280 + t + 192];
      float vv = red[1536 + t] + red[1536 + t + 64] + red[1536 + t + 128] + red[1536 + t + 192];
      ma = fmaxf(ma, 1e-20f);
      mb = fmaxf(mb, 1e-20f);
      float ib = 1.0f / (sqrtf(sc + EPSF) + EPSF);
      lsa[t] = 127.0f / ma;
      lsb[t] = 127.0f / mb;
      qsaG[j0 + t] = 127.0f / ma;
      effG[j0 + t] = (mb * (1.0f / 127.0f)) * ib;
      invbnG[j0 + t] = ib;
      rawNA[j0 + t] = sqrtf(sa);
      rawNB[j0 + t] = sqrtf(sb);
      uG[j0 + t] = uu;
      vG[j0 + t] = vv;
    }
  }

  // ---- phase 2: quantize + pack ----
  int wj = t >> 2;
  int wk = (t & 3) * 8;
  int p = j0 + wj;
  __syncthreads();
  float sa = lsa[wj];
  float sb = lsb[wj];
  int g = p >> 4;
  int laneB = p & 15;

  for (int c0 = 0; c0 < C_DIM; c0 += 32) {
    __syncthreads();
#pragma unroll
    for (int sIt = 0; sIt < 8; ++sIt) {
      int idx = t + sIt * 256;
      int r = idx >> 6, cc = idx & 63;
      la[cc * 33 + r] = x[(size_t)(c0 + r) * HW + j0 + cc];
      lb[cc * 33 + r] = s[(size_t)(c0 + r) * HW + j0 + cc];
    }
    __syncthreads();
    unsigned long long pkA = 0, pkB = 0;
#pragma unroll
    for (int uu = 0; uu < 8; ++uu) {
      int c = c0 + wk + uu;
      float av = (la[wj * 33 + wk + uu] - lma[c]) * sa;
      float bv = (lb[wj * 33 + wk + uu] - lmb[c]) * sb;
      int qA = (int)rintf(fminf(fmaxf(av, -127.f), 127.f));
      int qB = (int)rintf(fminf(fmaxf(bv, -127.f), 127.f));
      pkA |= ((unsigned long long)(unsigned char)(signed char)qA) << (8 * uu);
      pkB |= ((unsigned long long)(unsigned char)(signed char)qB) << (8 * uu);
    }
    *(unsigned long long*)(qa + (size_t)p * C_DIM + c0 + wk) = pkA;
    int k0 = c0 + wk;
    int sblk = k0 >> 6;
    int quad = (k0 & 63) >> 4;
    int e0 = k0 & 15;
    *(unsigned long long*)(Bp + (size_t)(g * 12 + sblk) * 1024 + (laneB | (quad << 4)) * 16 + e0) = pkB;
  }
}

// ---------------- Kernel G: i8 MFMA GEMM, LDS 4-ring, exact vmcnt ----------------
// 512 blocks (2/CU, 2 waves/SIMD via __launch_bounds__(256,2)). XCD swizzle:
// xcd=b&7, quarter=xcd>>1 (Bp quarter = 3MB, L2-resident; proven R5). Block owns
// 128 rows; wave w owns 32 (T_m=2, a_res=96 VGPR). B groups (12KB) stream through
// a 4-deep LDS ring staged by global_load_lds (3 instrs/wave/body — the ONLY vmem
// in the loop, so s_waitcnt vmcnt(6) + raw s_barrier is exact; prefetch distance
// 3 bodies). Ring overwrite is safe: barrier at body g => all waves consumed g-1.
__device__ __forceinline__ void gl_lds16(const void* g, void* l) {
  __builtin_amdgcn_global_load_lds((const __attribute__((address_space(1))) uint32_t*)g,
                                   (__attribute__((address_space(3))) uint32_t*)l, 16, 0, 0);
}

__global__ __launch_bounds__(256, 2) void k_gemm_argmax(
    const signed char* __restrict__ qa,
    const signed char* __restrict__ Bp,
    const float* __restrict__ eff,
    unsigned long long* __restrict__ best) {
  __shared__ signed char ringS[4 * 12288];   // 48 KB
  __shared__ float effL[4096];               // 16 KB
  int t = threadIdx.x;
  int lane = t & 63, w = t >> 6;
  int m = lane & 15, q = lane >> 4;
  int b = blockIdx.x;
  int xcd = b & 7;
  int bq = xcd >> 1;
  int rg = (b >> 3) | ((xcd & 1) << 6);      // 0..127
  int i0 = rg * 128;
  int g0 = bq * GPQ;
  int lane16 = lane * 16;
  int sW0 = (3 * w) * 1024 + lane16;

  // ---- A fragments: 2 tiles x 12 ksteps ----
  const i32x4* qaV = (const i32x4*)qa;
  i32x4 a_res[2][12];
#pragma unroll
  for (int tm = 0; tm < 2; ++tm) {
    int row = i0 + w * 32 + tm * 16 + m;
#pragma unroll
    for (int s = 0; s < 12; ++s)
      a_res[tm][s] = qaV[(size_t)row * 48 + s * 4 + q];
  }

  // ---- prologue: stage groups g0..g0+2 into ring slots 0..2; eff -> LDS ----
  {
    const signed char* ps = Bp + ((size_t)g0 * 12 + 3 * w) * 1024 + lane16;
#pragma unroll
    for (int gp = 0; gp < 3; ++gp) {
      signed char* dst = ringS + gp * 12288;
      gl_lds16(ps, dst + sW0);
      gl_lds16(ps + 1024, dst + sW0 + 1024);
      gl_lds16(ps + 2048, dst + sW0 + 2048);
      ps += 12288;
    }
  }
  for (int i = t; i < 4096; i += 256) effL[i] = eff[(g0 << 4) + i];
  __syncthreads();   // one-time full drain

  const signed char* srcW = Bp + ((size_t)(g0 + 3) * 12 + 3 * w) * 1024 + lane16;

  float bestv[2][4];
  int bestj[2][4];
#pragma unroll
  for (int tm = 0; tm < 2; ++tm)
#pragma unroll
    for (int r = 0; r < 4; ++r) { bestv[tm][r] = -3.0e38f; bestj[tm][r] = 0x7FFFFFFF; }

  int effOff = m;
  int jj = (g0 << 4) + m;

#define BODY(RB, VMSTR, DOSTAGE)                                                   \
  {                                                                                \
    asm volatile(VMSTR ::: "memory");                                              \
    __builtin_amdgcn_s_barrier();                                                  \
    const signed char* rb = ringS + (RB) * 12288;                                  \
    i32x4 f[12];                                                                   \
    _Pragma("unroll")                                                              \
    for (int s = 0; s < 12; ++s)                                                   \
      f[s] = *(const i32x4*)(rb + s * 1024 + lane16);                              \
    float ecur = effL[effOff];                                                     \
    i32x4 acc0 = {0, 0, 0, 0}, acc1 = {0, 0, 0, 0};                                \
    _Pragma("unroll")                                                              \
    for (int s = 0; s < 12; ++s) {                                                 \
      acc0 = __builtin_amdgcn_mfma_i32_16x16x64_i8(a_res[0][s], f[s], acc0, 0, 0, 0); \
      acc1 = __builtin_amdgcn_mfma_i32_16x16x64_i8(a_res[1][s], f[s], acc1, 0, 0, 0); \
    }                                                                              \
    if (DOSTAGE) {                                                                 \
      signed char* dst = ringS + (((RB) + 3) & 3) * 12288;                         \
      gl_lds16(srcW, dst + sW0);                                                   \
      gl_lds16(srcW + 1024, dst + sW0 + 1024);                                     \
      gl_lds16(srcW + 2048, dst + sW0 + 2048);                                     \
      srcW += 12288;                                                               \
    }                                                                              \
    _Pragma("unroll")                                                              \
    for (int r = 0; r < 4; ++r) {                                                  \
      float v0 = (float)acc0[r] * ecur;                                            \
      float v1 = (float)acc1[r] * ecur;                                            \
      if (v0 > bestv[0][r]) { bestv[0][r] = v0; bestj[0][r] = jj; }                \
      if (v1 > bestv[1][r]) { bestv[1][r] = v1; bestj[1][r] = jj; }                \
    }                                                                              \
    effOff += 16;                                                                  \
    jj += 16;                                                                      \
  }

  for (int mi = 0; mi < 63; ++mi) {
    BODY(0, "s_waitcnt vmcnt(6)", 1)
    BODY(1, "s_waitcnt vmcnt(6)", 1)
    BODY(2, "s_waitcnt vmcnt(6)", 1)
    BODY(3, "s_waitcnt vmcnt(6)", 1)
  }
  BODY(0, "s_waitcnt vmcnt(6)", 1)   // gl=252, stages group 255
  BODY(1, "s_waitcnt vmcnt(6)", 0)   // gl=253
  BODY(2, "s_waitcnt vmcnt(3)", 0)   // gl=254
  BODY(3, "s_waitcnt vmcnt(0)", 0)   // gl=255
#undef BODY

  // ---- reduce over 16 column-lanes, merge quarters via packed atomicMax ----
#pragma unroll
  for (int tm = 0; tm < 2; ++tm) {
#pragma unroll
    for (int r = 0; r < 4; ++r) {
      float bv = bestv[tm][r];
      int bj = bestj[tm][r];
#pragma unroll
      for (int off = 1; off < 16; off <<= 1) {
        float ov = __shfl_xor(bv, off, 64);
        int oj = __shfl_xor(bj, off, 64);
        if (ov > bv || (ov == bv && oj < bj)) { bv = ov; bj = oj; }
      }
      if (m == 0) {
        int i = i0 + w * 32 + tm * 16 + q * 4 + r;
        unsigned key = __float_as_uint(bv);
        key = (key & 0x80000000u) ? ~key : (key | 0x80000000u);
        unsigned long long packed =
            ((unsigned long long)key << 32) | (unsigned long long)(0xFFFFFFFFu - (unsigned)bj);
        atomicMax(&best[i], packed);
      }
    }
  }
}

// ---------------- Kernel D: final loss via analytic dot reconstruction ----------
__global__ __launch_bounds__(256) void k_loss2(const float* __restrict__ meanA,
                                               const float* __restrict__ meanB,
                                               const unsigned long long* __restrict__ best,
                                               const float* __restrict__ rawNA,
                                               const float* __restrict__ rawNB,
                                               const float* __restrict__ invbn,
                                               const float* __restrict__ qsa,
                                               const float* __restrict__ u,
                                               const float* __restrict__ v,
                                               float* __restrict__ out) {
  __shared__ float red[256];
  int t = threadIdx.x;
  float wp = 0.f;
  for (int c = t; c < C_DIM; c += 256) wp += meanA[c] * meanB[c];
  red[t] = wp;
  __syncthreads();
  for (int o = 128; o > 0; o >>= 1) {
    if (t < o) red[t] += red[t + o];
    __syncthreads();
  }
  float wdot = red[0];
  __syncthreads();

  int i = blockIdx.x * 256 + t;
  unsigned long long pk = best[i];
  unsigned key = (unsigned)(pk >> 32);
  unsigned fb = (key & 0x80000000u) ? (key & 0x7FFFFFFFu) : ~key;
  float bv = __uint_as_float(fb);
  int j = (int)(0xFFFFFFFFu - (unsigned)(pk & 0xFFFFFFFFull));
  float dotcc = bv / (invbn[j] * qsa[i]);
  float dot = dotcc + u[i] + v[j] + wdot;
  float cs = dot / ((rawNA[i] + EPSF) * (rawNB[j] + EPSF));
  red[t] = (1.0f - cs) * (1.0f / HW);
  __syncthreads();
  for (int o = 128; o > 0; o >>= 1) {
    if (t < o) red[t] += red[t + o];
    __syncthreads();
  }
  if (t == 0) atomicAdd(out, red[0]);
}

// ---------------- Launch ----------------
extern "C" void kernel_launch(void* const* d_in, const int* in_sizes, int n_in,
                              void* d_out, int out_size, void* d_ws, size_t ws_size,
                              hipStream_t stream) {
  const float* x = (const float*)d_in[0];
  const float* s = (const float*)d_in[1];
  char* ws = (char*)d_ws;
  float* meanA = (float*)(ws + 0);
  float* meanB = (float*)(ws + 4096);
  float* rawNA = (float*)(ws + 8192);
  float* rawNB = (float*)(ws + 73728);
  float* eff   = (float*)(ws + 139264);
  float* qsa   = (float*)(ws + 204800);
  float* invbn = (float*)(ws + 335872);
  float* u     = (float*)(ws + 401408);
  float* v     = (float*)(ws + 466944);
  unsigned long long* best = (unsigned long long*)(ws + 532480);
  signed char* qa = (signed char*)(ws + 663552);
  signed char* Bp = (signed char*)(ws + 663552 + 12582912);
  float* out = (float*)d_out;

  hipMemsetAsync(best, 0, HW * sizeof(unsigned long long), stream);
  hipMemsetAsync(out, 0, sizeof(float), stream);
  k_means<<<2 * C_DIM, 256, 0, stream>>>(x, s, meanA, meanB);
  k_prepq<<<HW / 64, 256, 0, stream>>>(x, s, meanA, meanB, qsa, eff, invbn, rawNA, rawNB, u, v, qa, Bp);
  k_gemm_argmax<<<512, 256, 0, stream>>>(qa, Bp, eff, best);
  k_loss2<<<HW / 256, 256, 0, stream>>>(meanA, meanB, best, rawNA, rawNB, invbn, qsa, u, v, out);
}

// Round 7
// 393.338 us; speedup vs baseline: 2.9824x; 1.0193x over previous
//
#include <hip/hip_runtime.h>
#include <hip/hip_bf16.h>
#include <stdint.h>

#define C_DIM 768
#define HW 16384
#define EPSF 1e-8f
#define GPQ 256            // groups (16 cols) per quarter

typedef __attribute__((ext_vector_type(4))) int i32x4;

// ---------------- Kernel A: per-channel means over spatial dim ----------------
__global__ __launch_bounds__(256) void k_means(const float* __restrict__ x,
                                               const float* __restrict__ s,
                                               float* __restrict__ meanA,
                                               float* __restrict__ meanB) {
  int ch = blockIdx.x;
  const float* src = (ch < C_DIM) ? (x + (size_t)ch * HW) : (s + (size_t)(ch - C_DIM) * HW);
  const float4* src4 = (const float4*)src;
  int t = threadIdx.x;
  float acc = 0.f;
  for (int i = t; i < HW / 4; i += 256) {
    float4 v = src4[i];
    acc += v.x + v.y + v.z + v.w;
  }
  __shared__ float red[256];
  red[t] = acc;
  __syncthreads();
  for (int o = 128; o > 0; o >>= 1) {
    if (t < o) red[t] += red[t + o];
    __syncthreads();
  }
  if (t == 0) {
    float m = red[0] * (1.0f / HW);
    if (ch < C_DIM) meanA[ch] = m; else meanB[ch - C_DIM] = m;
  }
}

// ---------------- Kernel P: fused stats + quantize + pack ----------------
// Phase 1: per-position stats. Phase 2: int8-LDS transpose: quantize at load,
// pack 4 channels/u32, ds_write_b32 (stride-40 rows), ds_read_b64, 8B stores.
__global__ __launch_bounds__(256) void k_prepq(const float* __restrict__ x,
                                               const float* __restrict__ s,
                                               const float* __restrict__ meanA,
                                               const float* __restrict__ meanB,
                                               float* __restrict__ qsaG,
                                               float* __restrict__ effG,
                                               float* __restrict__ invbnG,
                                               float* __restrict__ rawNA,
                                               float* __restrict__ rawNB,
                                               float* __restrict__ uG,
                                               float* __restrict__ vG,
                                               signed char* __restrict__ qa,
                                               signed char* __restrict__ Bp) {
  __shared__ float lma[C_DIM], lmb[C_DIM];
  __shared__ float red[7 * 256];
  __shared__ signed char tA8[64 * 40];
  __shared__ signed char tB8[64 * 40];
  __shared__ float lsa[64], lsb[64];
  int t = threadIdx.x;
  int j0 = blockIdx.x * 64;
  for (int c = t; c < C_DIM; c += 256) { lma[c] = meanA[c]; lmb[c] = meanB[c]; }
  __syncthreads();

  // ---- phase 1: stats ----
  {
    int pl = t & 63, cl = t >> 6;
    int p = j0 + pl;
    float maxa = 0.f, ssaR = 0.f, maxb = 0.f, ssbC = 0.f, ssbR = 0.f, uacc = 0.f, vacc = 0.f;
    for (int c = cl; c < C_DIM; c += 4) {
      float av = x[(size_t)c * HW + p];
      float bv = s[(size_t)c * HW + p];
      float ac = av - lma[c];
      float bc = bv - lmb[c];
      maxa = fmaxf(maxa, fabsf(ac));
      maxb = fmaxf(maxb, fabsf(bc));
      ssaR += av * av;
      ssbC += bc * bc;
      ssbR += bv * bv;
      uacc += ac * lmb[c];
      vacc += bc * lma[c];
    }
    red[t] = maxa; red[256 + t] = ssaR; red[512 + t] = maxb;
    red[768 + t] = ssbC; red[1024 + t] = ssbR; red[1280 + t] = uacc; red[1536 + t] = vacc;
    __syncthreads();
    if (t < 64) {
      float ma = fmaxf(fmaxf(red[t], red[t + 64]), fmaxf(red[t + 128], red[t + 192]));
      float sa = red[256 + t] + red[256 + t + 64] + red[256 + t + 128] + red[256 + t + 192];
      float mb = fmaxf(fmaxf(red[512 + t], red[512 + t + 64]), fmaxf(red[512 + t + 128], red[512 + t + 192]));
      float sc = red[768 + t] + red[768 + t + 64] + red[768 + t + 128] + red[768 + t + 192];
      float sb = red[1024 + t] + red[1024 + t + 64] + red[1024 + t + 128] + red[1024 + t + 192];
      float uu = red[1280 + t] + red[1280 + t + 64] + red[1280 + t + 128] + red[1280 + t + 192];
      float vv = red[1536 + t] + red[1536 + t + 64] + red[1536 + t + 128] + red[1536 + t + 192];
      ma = fmaxf(ma, 1e-20f);
      mb = fmaxf(mb, 1e-20f);
      float ib = 1.0f / (sqrtf(sc + EPSF) + EPSF);
      lsa[t] = 127.0f / ma;
      lsb[t] = 127.0f / mb;
      qsaG[j0 + t] = 127.0f / ma;
      effG[j0 + t] = (mb * (1.0f / 127.0f)) * ib;
      invbnG[j0 + t] = ib;
      rawNA[j0 + t] = sqrtf(sa);
      rawNB[j0 + t] = sqrtf(sb);
      uG[j0 + t] = uu;
      vG[j0 + t] = vv;
    }
  }
  __syncthreads();

  // ---- phase 2: quantize + transpose (int8 LDS) + pack ----
  int cc = t & 63;          // p within block (load side)
  int r4 = t >> 6;          // c-quad slot (load side)
  float sa = lsa[cc];
  float sb = lsb[cc];
  int pS = t >> 2;                 // row (store side)
  int ch8 = (t & 3) * 8;           // 8B chunk within 32B row (store side)
  int pgS = j0 + pS;
  int gS = pgS >> 4, laneS = pgS & 15;

  for (int c0 = 0; c0 < C_DIM; c0 += 32) {
    __syncthreads();   // tiles free (prev reads done)
#pragma unroll
    for (int v = 0; v < 2; ++v) {
      int q4 = r4 + 4 * v;
      unsigned pa = 0, pb = 0;
#pragma unroll
      for (int uu = 0; uu < 4; ++uu) {
        int c = c0 + q4 * 4 + uu;
        float av = (x[(size_t)c * HW + j0 + cc] - lma[c]) * sa;
        float bv = (s[(size_t)c * HW + j0 + cc] - lmb[c]) * sb;
        int qA = (int)rintf(fminf(fmaxf(av, -127.f), 127.f));
        int qB = (int)rintf(fminf(fmaxf(bv, -127.f), 127.f));
        pa |= ((unsigned)(unsigned char)(signed char)qA) << (8 * uu);
        pb |= ((unsigned)(unsigned char)(signed char)qB) << (8 * uu);
      }
      *(unsigned*)&tA8[cc * 40 + q4 * 4] = pa;
      *(unsigned*)&tB8[cc * 40 + q4 * 4] = pb;
    }
    __syncthreads();
    unsigned long long va = *(const unsigned long long*)&tA8[pS * 40 + ch8];
    *(unsigned long long*)(qa + (size_t)pgS * C_DIM + c0 + ch8) = va;
    unsigned long long vb = *(const unsigned long long*)&tB8[pS * 40 + ch8];
    int k0 = c0 + ch8;
    int sblk = k0 >> 6;
    int quad = (k0 & 63) >> 4;
    int e0 = k0 & 15;
    *(unsigned long long*)(Bp + (size_t)(gS * 12 + sblk) * 1024 + (laneS | (quad << 4)) * 16 + e0) = vb;
  }
}

// ---------------- Kernel G: i8 MFMA GEMM, LDS 4-ring, half-body pipeline --------
// As R6 (512 blocks, 2 waves/SIMD, XCD-swizzled L2-resident quarter, exact vmcnt)
// plus software pipelining: MFMA half-1 (fragments read LAST body) overlaps
// ds_read of half-2; MFMA half-2 overlaps ds_read of NEXT body's half-1.
// vmcnt(3) guarantees slot g AND g+1 landed at body g (stage-ahead 3).
__device__ __forceinline__ void gl_lds16(const void* g, void* l) {
  __builtin_amdgcn_global_load_lds((const __attribute__((address_space(1))) uint32_t*)g,
                                   (__attribute__((address_space(3))) uint32_t*)l, 16, 0, 0);
}

__global__ __launch_bounds__(256, 2) void k_gemm_argmax(
    const signed char* __restrict__ qa,
    const signed char* __restrict__ Bp,
    const float* __restrict__ eff,
    unsigned long long* __restrict__ best) {
  __shared__ signed char ringS[4 * 12288];   // 48 KB
  __shared__ float effL[4096];               // 16 KB
  int t = threadIdx.x;
  int lane = t & 63, w = t >> 6;
  int m = lane & 15, q = lane >> 4;
  int b = blockIdx.x;
  int xcd = b & 7;
  int bq = xcd >> 1;
  int rg = (b >> 3) | ((xcd & 1) << 6);      // 0..127
  int i0 = rg * 128;
  int g0 = bq * GPQ;
  int lane16 = lane * 16;
  int sW0 = (3 * w) * 1024 + lane16;

  // ---- A fragments: 2 tiles x 12 ksteps ----
  const i32x4* qaV = (const i32x4*)qa;
  i32x4 a_res[2][12];
#pragma unroll
  for (int tm = 0; tm < 2; ++tm) {
    int row = i0 + w * 32 + tm * 16 + m;
#pragma unroll
    for (int s = 0; s < 12; ++s)
      a_res[tm][s] = qaV[(size_t)row * 48 + s * 4 + q];
  }

  // ---- prologue: stage groups g0..g0+2 into ring slots 0..2; eff -> LDS ----
  {
    const signed char* ps = Bp + ((size_t)g0 * 12 + 3 * w) * 1024 + lane16;
#pragma unroll
    for (int gp = 0; gp < 3; ++gp) {
      signed char* dst = ringS + gp * 12288;
      gl_lds16(ps, dst + sW0);
      gl_lds16(ps + 1024, dst + sW0 + 1024);
      gl_lds16(ps + 2048, dst + sW0 + 2048);
      ps += 12288;
    }
  }
  for (int i = t; i < 4096; i += 256) effL[i] = eff[(g0 << 4) + i];
  __syncthreads();   // one-time full drain (vmcnt back to 0 outstanding)

  const signed char* srcW = Bp + ((size_t)(g0 + 3) * 12 + 3 * w) * 1024 + lane16;

  float bestv[2][4];
  int bestj[2][4];
#pragma unroll
  for (int tm = 0; tm < 2; ++tm)
#pragma unroll
    for (int r = 0; r < 4; ++r) { bestv[tm][r] = -3.0e38f; bestj[tm][r] = 0x7FFFFFFF; }

  int effOff = m;
  int jj = (g0 << 4) + m;

  // fA: ks0-5 of current body's slot (read during PREVIOUS body)
  // fB: ks6-11 of current body's slot (read during this body, phase A)
  i32x4 fA[6], fB[6];
#pragma unroll
  for (int s = 0; s < 6; ++s) fA[s] = *(const i32x4*)(ringS + s * 1024 + lane16);

#define BODY(SLOT, VMSTR, DOSTAGE, DOAHEAD)                                        \
  {                                                                                \
    asm volatile(VMSTR ::: "memory");                                              \
    __builtin_amdgcn_s_barrier();                                                  \
    const signed char* rb = ringS + (SLOT) * 12288;                                \
    _Pragma("unroll")                                                              \
    for (int s = 0; s < 6; ++s)                                                    \
      fB[s] = *(const i32x4*)(rb + (6 + s) * 1024 + lane16);                       \
    if (DOSTAGE) {                                                                 \
      signed char* dst = ringS + (((SLOT) + 3) & 3) * 12288;                       \
      gl_lds16(srcW, dst + sW0);                                                   \
      gl_lds16(srcW + 1024, dst + sW0 + 1024);                                     \
      gl_lds16(srcW + 2048, dst + sW0 + 2048);                                     \
      srcW += 12288;                                                               \
    }                                                                              \
    i32x4 acc0 = {0, 0, 0, 0}, acc1 = {0, 0, 0, 0};                                \
    _Pragma("unroll")                                                              \
    for (int s = 0; s < 6; ++s) {                                                  \
      acc0 = __builtin_amdgcn_mfma_i32_16x16x64_i8(a_res[0][s], fA[s], acc0, 0, 0, 0); \
      acc1 = __builtin_amdgcn_mfma_i32_16x16x64_i8(a_res[1][s], fA[s], acc1, 0, 0, 0); \
    }                                                                              \
    if (DOAHEAD) {                                                                 \
      const signed char* rn = ringS + (((SLOT) + 1) & 3) * 12288;                  \
      _Pragma("unroll")                                                            \
      for (int s = 0; s < 6; ++s)                                                  \
        fA[s] = *(const i32x4*)(rn + s * 1024 + lane16);                           \
    }                                                                              \
    _Pragma("unroll")                                                              \
    for (int s = 0; s < 6; ++s) {                                                  \
      acc0 = __builtin_amdgcn_mfma_i32_16x16x64_i8(a_res[0][6 + s], fB[s], acc0, 0, 0, 0); \
      acc1 = __builtin_amdgcn_mfma_i32_16x16x64_i8(a_res[1][6 + s], fB[s], acc1, 0, 0, 0); \
    }                                                                              \
    float ecur = effL[effOff];                                                     \
    _Pragma("unroll")                                                              \
    for (int r = 0; r < 4; ++r) {                                                  \
      float v0 = (float)acc0[r] * ecur;                                            \
      float v1 = (float)acc1[r] * ecur;                                            \
      if (v0 > bestv[0][r]) { bestv[0][r] = v0; bestj[0][r] = jj; }                \
      if (v1 > bestv[1][r]) { bestv[1][r] = v1; bestj[1][r] = jj; }                \
    }                                                                              \
    effOff += 16;                                                                  \
    jj += 16;                                                                      \
  }

  for (int mi = 0; mi < 63; ++mi) {      // bodies 0..251
    BODY(0, "s_waitcnt vmcnt(3)", 1, 1)
    BODY(1, "s_waitcnt vmcnt(3)", 1, 1)
    BODY(2, "s_waitcnt vmcnt(3)", 1, 1)
    BODY(3, "s_waitcnt vmcnt(3)", 1, 1)
  }
  BODY(0, "s_waitcnt vmcnt(3)", 1, 1)    // body 252 (stages slot 255)
  BODY(1, "s_waitcnt vmcnt(3)", 0, 1)    // body 253
  BODY(2, "s_waitcnt vmcnt(0)", 0, 1)    // body 254
  BODY(3, "s_waitcnt vmcnt(0)", 0, 0)    // body 255
#undef BODY

  // ---- reduce over 16 column-lanes, merge quarters via packed atomicMax ----
#pragma unroll
  for (int tm = 0; tm < 2; ++tm) {
#pragma unroll
    for (int r = 0; r < 4; ++r) {
      float bv = bestv[tm][r];
      int bj = bestj[tm][r];
#pragma unroll
      for (int off = 1; off < 16; off <<= 1) {
        float ov = __shfl_xor(bv, off, 64);
        int oj = __shfl_xor(bj, off, 64);
        if (ov > bv || (ov == bv && oj < bj)) { bv = ov; bj = oj; }
      }
      if (m == 0) {
        int i = i0 + w * 32 + tm * 16 + q * 4 + r;
        unsigned key = __float_as_uint(bv);
        key = (key & 0x80000000u) ? ~key : (key | 0x80000000u);
        unsigned long long packed =
            ((unsigned long long)key << 32) | (unsigned long long)(0xFFFFFFFFu - (unsigned)bj);
        atomicMax(&best[i], packed);
      }
    }
  }
}

// ---------------- Kernel D: final loss via analytic dot reconstruction ----------
__global__ __launch_bounds__(256) void k_loss2(const float* __restrict__ meanA,
                                               const float* __restrict__ meanB,
                                               const unsigned long long* __restrict__ best,
                                               const float* __restrict__ rawNA,
                                               const float* __restrict__ rawNB,
                                               const float* __restrict__ invbn,
                                               const float* __restrict__ qsa,
                                               const float* __restrict__ u,
                                               const float* __restrict__ v,
                                               float* __restrict__ out) {
  __shared__ float red[256];
  int t = threadIdx.x;
  float wp = 0.f;
  for (int c = t; c < C_DIM; c += 256) wp += meanA[c] * meanB[c];
  red[t] = wp;
  __syncthreads();
  for (int o = 128; o > 0; o >>= 1) {
    if (t < o) red[t] += red[t + o];
    __syncthreads();
  }
  float wdot = red[0];
  __syncthreads();

  int i = blockIdx.x * 256 + t;
  unsigned long long pk = best[i];
  unsigned key = (unsigned)(pk >> 32);
  unsigned fb = (key & 0x80000000u) ? (key & 0x7FFFFFFFu) : ~key;
  float bv = __uint_as_float(fb);
  int j = (int)(0xFFFFFFFFu - (unsigned)(pk & 0xFFFFFFFFull));
  float dotcc = bv / (invbn[j] * qsa[i]);
  float dot = dotcc + u[i] + v[j] + wdot;
  float cs = dot / ((rawNA[i] + EPSF) * (rawNB[j] + EPSF));
  red[t] = (1.0f - cs) * (1.0f / HW);
  __syncthreads();
  for (int o = 128; o > 0; o >>= 1) {
    if (t < o) red[t] += red[t + o];
    __syncthreads();
  }
  if (t == 0) atomicAdd(out, red[0]);
}

// ---------------- Launch ----------------
extern "C" void kernel_launch(void* const* d_in, const int* in_sizes, int n_in,
                              void* d_out, int out_size, void* d_ws, size_t ws_size,
                              hipStream_t stream) {
  const float* x = (const float*)d_in[0];
  const float* s = (const float*)d_in[1];
  char* ws = (char*)d_ws;
  float* meanA = (float*)(ws + 0);
  float* meanB = (float*)(ws + 4096);
  float* rawNA = (float*)(ws + 8192);
  float* rawNB = (float*)(ws + 73728);
  float* eff   = (float*)(ws + 139264);
  float* qsa   = (float*)(ws + 204800);
  float* invbn = (float*)(ws + 335872);
  float* u     = (float*)(ws + 401408);
  float* v     = (float*)(ws + 466944);
  unsigned long long* best = (unsigned long long*)(ws + 532480);
  signed char* qa = (signed char*)(ws + 663552);
  signed char* Bp = (signed char*)(ws + 663552 + 12582912);
  float* out = (float*)d_out;

  hipMemsetAsync(best, 0, HW * sizeof(unsigned long long), stream);
  hipMemsetAsync(out, 0, sizeof(float), stream);
  k_means<<<2 * C_DIM, 256, 0, stream>>>(x, s, meanA, meanB);
  k_prepq<<<HW / 64, 256, 0, stream>>>(x, s, meanA, meanB, qsa, eff, invbn, rawNA, rawNB, u, v, qa, Bp);
  k_gemm_argmax<<<512, 256, 0, stream>>>(qa, Bp, eff, best);
  k_loss2<<<HW / 256, 256, 0, stream>>>(meanA, meanB, best, rawNA, rawNB, invbn, qsa, u, v, out);
}